// Round 4
// baseline (910.147 us; speedup 1.0000x reference)
//
#include <hip/hip_runtime.h>
#include <hip/hip_bf16.h>

#define TB 256
#define BM 64
#define BK 32
#define BN 128
#define ASTR 68   // BM + 4 (fp32 path, k1/k6)
#define MAXD 160  // per-node edge cache for k5

static constexpr int NN = 20000;
static constexpr int NE = 320000;

// workspace layout (floats)
static constexpr long long OFF_HN   = 0;          // N*128 fp32
static constexpr long long OFF_OW   = 2560000;    // owH/owL bf16: E*128 ushort each (40.96M floats total)
static constexpr long long OFF_S    = 43520000;   // E  (raw attention scalar s)
static constexpr long long OFF_DEN  = 43840000;   // N
static constexpr long long OFF_CUR  = 43860000;   // N ints
static constexpr long long OFF_HAGG = 43880000;   // N*256  (ends 49,000,000)
static constexpr long long OFF_WT   = 49000000;   // split-bf16 transposed weights (ushort)
static constexpr long long WS_FLOATS = 49140000;  // ~196.6 MB (proven budget)

// Wt sub-offsets in ushort units from OFF_WT base
static constexpr int U_E = 0;        // W_eedge^T hi [128][128]; lo at +16384
static constexpr int U_F = 32768;    // W_fuse^T  hi [128][384]; lo at +49152
static constexpr int U_A = 131072;   // W_aggre^T hi [128][512]; lo at +65536

// d_out layout (floats): h_out, w_out, sat
static constexpr long long OUT_HOUT = 0;
static constexpr long long OUT_WOUT = 2560000;    // holds w2 until k7 overwrites with w_out
static constexpr long long OUT_SAT  = 43520000;

typedef __attribute__((ext_vector_type(8))) short s8v;      // 8 bf16 (4 VGPR)
typedef __attribute__((ext_vector_type(4))) float f32x4;

#define MFMA16(a,b,c) __builtin_amdgcn_mfma_f32_16x16x32_bf16(a,b,c,0,0,0)

__device__ __forceinline__ float lrelu(float x){ return x >= 0.f ? x : 0.1f*x; }

// ---- split fp32 -> (hi,lo) bf16, RNE both; hi+lo carries ~17 mantissa bits ----
__device__ __forceinline__ void split1(float f, unsigned short& hi, unsigned short& lo){
    __hip_bfloat16 h = __float2bfloat16(f);
    float hf = __bfloat162float(h);
    __hip_bfloat16 l = __float2bfloat16(f - hf);
    hi = __builtin_bit_cast(unsigned short, h);
    lo = __builtin_bit_cast(unsigned short, l);
}
__device__ __forceinline__ void split8(float4 a, float4 b, s8v& hi, s8v& lo){
    float v[8] = {a.x,a.y,a.z,a.w,b.x,b.y,b.z,b.w};
#pragma unroll
    for (int j = 0; j < 8; ++j){
        unsigned short hs, ls;
        split1(v[j], hs, ls);
        hi[j] = (short)hs; lo[j] = (short)ls;
    }
}

// LDS tile addressing: [128 rows][32 k] bf16, 16B-slot XOR swizzle (T2 family)
__device__ __forceinline__ int lds_a(int row, int g){
    return row*32 + ((g ^ (row & 3)) << 3);   // ushort index, 16B aligned
}

// ================= fp32 helpers for k1/k6 =================
__device__ __forceinline__ void store_At(float (*Ast)[ASTR], int k4, int r, float4 v){
    Ast[k4+0][r] = v.x; Ast[k4+1][r] = v.y; Ast[k4+2][r] = v.z; Ast[k4+3][r] = v.w;
}
__device__ __forceinline__ void mm_chunk(const float (*Ast)[ASTR], const float (*Bs)[BN],
                                         int r0, int c0, float acc[4][8]){
#pragma unroll 4
    for (int k = 0; k < BK; ++k){
        const float4 av = *(const float4*)&Ast[k][r0];
        const float4 b0 = *(const float4*)&Bs[k][c0];
        const float4 b1 = *(const float4*)&Bs[k][64 + c0];
        const float a0=av.x, a1=av.y, a2=av.z, a3=av.w;
        const float b[8] = {b0.x,b0.y,b0.z,b0.w,b1.x,b1.y,b1.z,b1.w};
#pragma unroll
        for (int j = 0; j < 8; ++j){
            acc[0][j] = fmaf(a0, b[j], acc[0][j]);
            acc[1][j] = fmaf(a1, b[j], acc[1][j]);
            acc[2][j] = fmaf(a2, b[j], acc[2][j]);
            acc[3][j] = fmaf(a3, b[j], acc[3][j]);
        }
    }
}
__device__ __forceinline__ void load_B(const float* __restrict__ W, int kc,
                                       float (*Bs)[BN], int tid){
#pragma unroll
    for (int p = 0; p < 4; ++p){
        int idx = p*TB + tid;
        int row = idx >> 5;
        int c4  = (idx & 31) << 2;
        *(float4*)&Bs[row][c4] = *(const float4*)&W[(size_t)(kc+row)*BN + c4];
    }
}

// block-wide reductions (k5)
__device__ __forceinline__ float blockMax(float v, float* sh4){
#pragma unroll
    for (int m = 32; m; m >>= 1) v = fmaxf(v, __shfl_xor(v, m));
    if ((threadIdx.x & 63) == 0) sh4[threadIdx.x >> 6] = v;
    __syncthreads();
    float r = fmaxf(fmaxf(sh4[0], sh4[1]), fmaxf(sh4[2], sh4[3]));
    __syncthreads();
    return r;
}
__device__ __forceinline__ float blockSum(float v, float* sh4){
#pragma unroll
    for (int m = 32; m; m >>= 1) v += __shfl_xor(v, m);
    if ((threadIdx.x & 63) == 0) sh4[threadIdx.x >> 6] = v;
    __syncthreads();
    float r = sh4[0] + sh4[1] + sh4[2] + sh4[3];
    __syncthreads();
    return r;
}

// ---------------- k_prep: cur init + all three weight transpose/splits ----------------
__global__ __launch_bounds__(TB) void k_prep(const float* __restrict__ We,
                                             const float* __restrict__ Wf,
                                             const float* __restrict__ Wa,
                                             unsigned short* __restrict__ wt,
                                             int* __restrict__ cur){
    int id = blockIdx.x*TB + threadIdx.x;   // grid covers 131072
    if (id < NN) cur[id] = 0;
    unsigned short hs, ls;
    if (id < 16384){                       // W_eedge: K=128
        int n = id >> 7, k = id & 127;
        split1(We[(size_t)k*128 + n], hs, ls);
        wt[U_E + id] = hs; wt[U_E + 16384 + id] = ls;
    } else if (id < 65536){                // W_fuse: K=384
        int local = id - 16384;
        int n = local / 384, k = local - n*384;
        split1(Wf[(size_t)k*128 + n], hs, ls);
        wt[U_F + local] = hs; wt[U_F + 49152 + local] = ls;
    } else if (id < 131072){               // W_aggre: K=512
        int local = id - 65536;
        int n = local >> 9, k = local & 511;
        split1(Wa[(size_t)k*128 + n], hs, ls);
        wt[U_A + local] = hs; wt[U_A + 65536 + local] = ls;
    }
}

// ---------------- sort pipeline ----------------
__global__ __launch_bounds__(TB) void kB_count(const int* __restrict__ dst,
                                               int* __restrict__ cur){
    int e = blockIdx.x*TB + threadIdx.x;
    atomicAdd(&cur[dst[e]], 1);
}
__global__ __launch_bounds__(TB) void kC_scan(int* __restrict__ cur,
                                              int* __restrict__ offs){
    __shared__ int part[TB];
    __shared__ int spre[TB];
    const int tid = threadIdx.x;
    const int CH = (NN + TB - 1) / TB;
    const int base = tid * CH;
    int sum = 0;
    for (int i = 0; i < CH; ++i){ int idx = base + i; if (idx < NN) sum += cur[idx]; }
    part[tid] = sum;
    __syncthreads();
    if (tid == 0){ int r = 0; for (int i = 0; i < TB; ++i){ spre[i] = r; r += part[i]; } }
    __syncthreads();
    int run = spre[tid];
    for (int i = 0; i < CH; ++i){
        int idx = base + i;
        if (idx < NN){ int c = cur[idx]; offs[idx] = run; cur[idx] = run; run += c; }
    }
}
__global__ __launch_bounds__(TB) void kD_scatter(const int* __restrict__ dst,
                                                 int* __restrict__ cur,
                                                 int* __restrict__ eidx){
    int e = blockIdx.x*TB + threadIdx.x;
    int p = atomicAdd(&cur[dst[e]], 1);
    eidx[p] = e;
}

// ---------------- k1: hn = h @ W_node (fp32 path) ----------------
__global__ __launch_bounds__(TB) void k1_hn(const float* __restrict__ h,
                                            const float* __restrict__ Wn,
                                            float* __restrict__ hn){
    __shared__ float Ast[BK][ASTR];
    __shared__ float Bs[BK][BN];
    const int tid = threadIdx.x;
    const int rbase = blockIdx.x * BM;
    const int tc = tid & 15, tr = tid >> 4;
    const int r0 = tr*4, c0 = tc*4;
    float acc[4][8] = {};
    for (int kc = 0; kc < 128; kc += BK){
        __syncthreads();
        {
            int lr = tid >> 3, k4 = (tid & 7) << 2;
#pragma unroll
            for (int p = 0; p < 2; ++p){
                int r = p*32 + lr;
                int rr = rbase + r; if (rr >= NN) rr = NN-1;
                float4 v = *(const float4*)&h[(size_t)rr*128 + kc + k4];
                store_At(Ast, k4, r, v);
            }
        }
        load_B(Wn, kc, Bs, tid);
        __syncthreads();
        mm_chunk(Ast, Bs, r0, c0, acc);
    }
#pragma unroll
    for (int i = 0; i < 4; ++i){
        int rr = rbase + r0 + i;
        if (rr < NN){
            float4 o0 = {acc[i][0],acc[i][1],acc[i][2],acc[i][3]};
            float4 o1 = {acc[i][4],acc[i][5],acc[i][6],acc[i][7]};
            *(float4*)&hn[(size_t)rr*128 + c0] = o0;
            *(float4*)&hn[(size_t)rr*128 + 64 + c0] = o1;
        }
    }
}

// ================== k23: fused edge GEMMs ==================
// GEMM1: ow = edge_w @ W_eedge; w1 = (lrelu(ow)@W_esf)*ow  (ow stored split-bf16 only)
// GEMM2: sat=[hs,hd,w1]; inw=lrelu(sat@W_fuse+b); a=inw@W_attn; w2=a*w1; s=a
__global__ __launch_bounds__(TB) void k23_fuse(const float* __restrict__ ew,
                                               const unsigned short* __restrict__ wtE_H,
                                               const unsigned short* __restrict__ wtE_L,
                                               const float* __restrict__ Wesf,
                                               const unsigned short* __restrict__ wtF_H,
                                               const unsigned short* __restrict__ wtF_L,
                                               const float* __restrict__ bf,
                                               const float* __restrict__ Wattn,
                                               const int* __restrict__ src,
                                               const int* __restrict__ dst,
                                               const float* __restrict__ hn,
                                               unsigned short* __restrict__ owH,
                                               unsigned short* __restrict__ owL,
                                               float* __restrict__ sat,
                                               float* __restrict__ w2,
                                               float* __restrict__ s_ws){
    __shared__ __align__(16) unsigned short Ah[4096], Al[4096], Bh[4096], Bl[4096];
    __shared__ float sEsf[128], sBf[128], sAtt[128];
    __shared__ int sSrc[128], sDst[128];
    const int tid = threadIdx.x;
    const long long rbase = (long long)blockIdx.x * 128;
    const int lane = tid & 63, w = tid >> 6;
    const int ls = lane & 15, lg = lane >> 4;
    if (tid < 128){
        sEsf[tid] = Wesf[tid]; sBf[tid] = bf[tid]; sAtt[tid] = Wattn[tid];
        sSrc[tid] = src[rbase + tid]; sDst[tid] = dst[rbase + tid];
    }
    f32x4 acc[2][8] = {};
    // ---- GEMM1: K=128 (edge_w) ----
    for (int kc = 0; kc < 128; kc += 32){
        __syncthreads();
#pragma unroll
        for (int u = 0; u < 2; ++u){
            int id = tid + u*256;
            int row = id >> 2, g = id & 3;
            int kk = kc + g*8;
            const float* p = &ew[(rbase + row)*128 + kk];
            float4 v0 = *(const float4*)p, v1 = *(const float4*)(p+4);
            s8v hi, lo; split8(v0, v1, hi, lo);
            *(s8v*)&Ah[lds_a(row,g)] = hi; *(s8v*)&Al[lds_a(row,g)] = lo;
            int col = row;
            *(s8v*)&Bh[lds_a(col,g)] = *(const s8v*)&wtE_H[col*128 + kk];
            *(s8v*)&Bl[lds_a(col,g)] = *(const s8v*)&wtE_L[col*128 + kk];
        }
        __syncthreads();
        s8v ah[2], al[2];
#pragma unroll
        for (int rt = 0; rt < 2; ++rt){
            int r = w*32 + rt*16 + ls;
            ah[rt] = *(const s8v*)&Ah[lds_a(r,lg)];
            al[rt] = *(const s8v*)&Al[lds_a(r,lg)];
        }
#pragma unroll
        for (int ct = 0; ct < 8; ++ct){
            int c = ct*16 + ls;
            s8v bh = *(const s8v*)&Bh[lds_a(c,lg)];
            s8v bl = *(const s8v*)&Bl[lds_a(c,lg)];
#pragma unroll
            for (int rt = 0; rt < 2; ++rt){
                acc[rt][ct] = MFMA16(ah[rt], bh, acc[rt][ct]);
                acc[rt][ct] = MFMA16(ah[rt], bl, acc[rt][ct]);
                acc[rt][ct] = MFMA16(al[rt], bh, acc[rt][ct]);
            }
        }
    }
    // ---- epilogue 1: w1 = (lrelu(ow)@W_esf)*ow; store sat_w1 fp32 + ow split-bf16 ----
#pragma unroll
    for (int rt = 0; rt < 2; ++rt){
#pragma unroll
        for (int reg = 0; reg < 4; ++reg){
            float p = 0.f;
#pragma unroll
            for (int ct = 0; ct < 8; ++ct)
                p += lrelu(acc[rt][ct][reg]) * sEsf[ct*16 + ls];
#pragma unroll
            for (int m = 1; m < 16; m <<= 1) p += __shfl_xor(p, m);
            long long orow = rbase + w*32 + rt*16 + lg*4 + reg;
#pragma unroll
            for (int ct = 0; ct < 8; ++ct){
                float o = acc[rt][ct][reg];
                int col = ct*16 + ls;
                sat[orow*384 + 256 + col] = p * o;
                unsigned short hsv, lsv; split1(o, hsv, lsv);
                owH[orow*128 + col] = hsv;
                owL[orow*128 + col] = lsv;
            }
        }
    }
    __threadfence_block();   // make sat_w1 visible to this block's GEMM2 reads
    // ---- GEMM2: K=384 ([hs, hd, w1] @ W_fuse) ----
#pragma unroll
    for (int rt = 0; rt < 2; ++rt)
#pragma unroll
        for (int ct = 0; ct < 8; ++ct)
            acc[rt][ct] = (f32x4){0.f, 0.f, 0.f, 0.f};
    for (int kc = 0; kc < 384; kc += 32){
        __syncthreads();
#pragma unroll
        for (int u = 0; u < 2; ++u){
            int id = tid + u*256;
            int row = id >> 2, g = id & 3;
            int kk = kc + g*8;
            long long e = rbase + row;
            float4 v0, v1;
            if (kk < 128){
                const float* p = &hn[(size_t)sSrc[row]*128 + kk];
                v0 = *(const float4*)p; v1 = *(const float4*)(p+4);
                *(float4*)&sat[e*384 + kk] = v0; *(float4*)&sat[e*384 + kk + 4] = v1;
            } else if (kk < 256){
                const float* p = &hn[(size_t)sDst[row]*128 + (kk-128)];
                v0 = *(const float4*)p; v1 = *(const float4*)(p+4);
                *(float4*)&sat[e*384 + kk] = v0; *(float4*)&sat[e*384 + kk + 4] = v1;
            } else {
                const float* p = &sat[e*384 + kk];   // w1: L1/L2-hot (this block wrote it)
                v0 = *(const float4*)p; v1 = *(const float4*)(p+4);
            }
            s8v hi, lo; split8(v0, v1, hi, lo);
            *(s8v*)&Ah[lds_a(row,g)] = hi; *(s8v*)&Al[lds_a(row,g)] = lo;
            int col = row;
            *(s8v*)&Bh[lds_a(col,g)] = *(const s8v*)&wtF_H[col*384 + kk];
            *(s8v*)&Bl[lds_a(col,g)] = *(const s8v*)&wtF_L[col*384 + kk];
        }
        __syncthreads();
        s8v ah[2], al[2];
#pragma unroll
        for (int rt = 0; rt < 2; ++rt){
            int r = w*32 + rt*16 + ls;
            ah[rt] = *(const s8v*)&Ah[lds_a(r,lg)];
            al[rt] = *(const s8v*)&Al[lds_a(r,lg)];
        }
#pragma unroll
        for (int ct = 0; ct < 8; ++ct){
            int c = ct*16 + ls;
            s8v bh = *(const s8v*)&Bh[lds_a(c,lg)];
            s8v bl = *(const s8v*)&Bl[lds_a(c,lg)];
#pragma unroll
            for (int rt = 0; rt < 2; ++rt){
                acc[rt][ct] = MFMA16(ah[rt], bh, acc[rt][ct]);
                acc[rt][ct] = MFMA16(ah[rt], bl, acc[rt][ct]);
                acc[rt][ct] = MFMA16(al[rt], bh, acc[rt][ct]);
            }
        }
    }
    // ---- epilogue 2: attn dot -> s; w2 = a * w1 ----
#pragma unroll
    for (int rt = 0; rt < 2; ++rt){
#pragma unroll
        for (int reg = 0; reg < 4; ++reg){
            float p = 0.f;
#pragma unroll
            for (int ct = 0; ct < 8; ++ct){
                int col = ct*16 + ls;
                p += lrelu(acc[rt][ct][reg] + sBf[col]) * sAtt[col];
            }
#pragma unroll
            for (int m = 1; m < 16; m <<= 1) p += __shfl_xor(p, m);
            long long orow = rbase + w*32 + rt*16 + lg*4 + reg;
            if (ls == 0) s_ws[orow] = p;
#pragma unroll
            for (int ct = 0; ct < 8; ++ct){
                int col = ct*16 + ls;
                float w1v = sat[orow*384 + 256 + col];   // L1-hot
                w2[orow*128 + col] = p * w1v;
            }
        }
    }
}

// ---------------- k5: per-node softmax + gather-aggregate ----------------
__global__ __launch_bounds__(TB) void k5_agg(const float* __restrict__ s,
                                             const float* __restrict__ hn,
                                             const float* __restrict__ w2,
                                             const int* __restrict__ src,
                                             const int* __restrict__ eidx,
                                             const int* __restrict__ offs,
                                             const int* __restrict__ cur,
                                             float* __restrict__ hagg,
                                             float* __restrict__ den){
    __shared__ int   sE[MAXD];
    __shared__ int   sSrc[MAXD];
    __shared__ float sA[MAXD];
    __shared__ float sh4[4];
    const int n = blockIdx.x, tid = threadIdx.x;
    const int start = offs[n];
    const int deg = cur[n] - start;
    for (int i = tid; i < deg && i < MAXD; i += TB) sE[i] = eidx[start+i];
    __syncthreads();
    if (tid == 0 && deg > 1){
        int dd = deg < MAXD ? deg : MAXD;
        for (int i = 1; i < dd; ++i){
            int key = sE[i], j = i-1;
            while (j >= 0 && sE[j] > key){ sE[j+1] = sE[j]; --j; }
            sE[j+1] = key;
        }
    }
    __syncthreads();
    float lm = -3.402823466e38f;
    for (int i = tid; i < deg; i += TB){
        int e = (i < MAXD) ? sE[i] : eidx[start+i];
        lm = fmaxf(lm, s[e]);
    }
    const float m = blockMax(lm, sh4);
    float lsum = 0.f;
    for (int i = tid; i < deg; i += TB){
        int e = (i < MAXD) ? sE[i] : eidx[start+i];
        lsum += expf(s[e] - m);
    }
    const float denom = blockSum(lsum, sh4);
    for (int i = tid; i < deg && i < MAXD; i += TB){
        int e = sE[i];
        sA[i] = expf(s[e] - m) / denom;
        sSrc[i] = src[e];
    }
    __syncthreads();
    float acc = 0.f;
    const bool lo = tid < 128;
    for (int i = 0; i < deg; ++i){
        int e, sI; float a;
        if (i < MAXD){ e = sE[i]; a = sA[i]; sI = sSrc[i]; }
        else { e = eidx[start+i]; a = expf(s[e]-m)/denom; sI = src[e]; }
        float v = lo ? hn[(size_t)sI*128 + tid] : w2[(size_t)e*128 + (tid-128)];
        acc = fmaf(a, v, acc);
    }
    hagg[(size_t)n*256 + tid] = acc;
    if (tid == 0) den[n] = (deg > 0) ? denom : 0.f;
}

// ---------------- k6: h_new = [h_agg, hn] @ W_conc + b_conc ; indeg select ----------------
__global__ __launch_bounds__(TB) void k6_conc(const float* __restrict__ hagg,
                                              const float* __restrict__ hn,
                                              const float* __restrict__ Wc,
                                              const float* __restrict__ bc,
                                              const float* __restrict__ den,
                                              float* __restrict__ hout){
    __shared__ float Ast[BK][ASTR];
    __shared__ float Bs[BK][BN];
    __shared__ float sBc[BN];
    const int tid = threadIdx.x;
    const int rbase = blockIdx.x * BM;
    const int tc = tid & 15, tr = tid >> 4;
    const int r0 = tr*4, c0 = tc*4;
    if (tid < BN) sBc[tid] = bc[tid];
    float acc[4][8] = {};
    for (int chunk = 0; chunk < 12; ++chunk){
        int kc = chunk * BK;
        __syncthreads();
        {
            int lr = tid >> 3, k4 = (tid & 7) << 2;
#pragma unroll
            for (int p = 0; p < 2; ++p){
                int r = p*32 + lr;
                int rr = rbase + r; if (rr >= NN) rr = NN-1;
                float4 v;
                if (chunk < 8) v = *(const float4*)&hagg[(size_t)rr*256 + kc + k4];
                else           v = *(const float4*)&hn[(size_t)rr*128 + (kc-256) + k4];
                store_At(Ast, k4, r, v);
            }
        }
        load_B(Wc, kc, Bs, tid);
        __syncthreads();
        mm_chunk(Ast, Bs, r0, c0, acc);
    }
#pragma unroll
    for (int i = 0; i < 4; ++i){
        int rr = rbase + r0 + i;
        if (rr >= NN) continue;
        bool keep = den[rr] > 0.f;
        float4 h0 = *(const float4*)&hn[(size_t)rr*128 + c0];
        float4 h1 = *(const float4*)&hn[(size_t)rr*128 + 64 + c0];
        float4 o0, o1;
        o0.x = keep ? acc[i][0] + sBc[c0+0] : h0.x;
        o0.y = keep ? acc[i][1] + sBc[c0+1] : h0.y;
        o0.z = keep ? acc[i][2] + sBc[c0+2] : h0.z;
        o0.w = keep ? acc[i][3] + sBc[c0+3] : h0.w;
        o1.x = keep ? acc[i][4] + sBc[64+c0+0] : h1.x;
        o1.y = keep ? acc[i][5] + sBc[64+c0+1] : h1.y;
        o1.z = keep ? acc[i][6] + sBc[64+c0+2] : h1.z;
        o1.w = keep ? acc[i][7] + sBc[64+c0+3] : h1.w;
        *(float4*)&hout[(size_t)rr*128 + c0] = o0;
        *(float4*)&hout[(size_t)rr*128 + 64 + c0] = o1;
    }
}

// ---------------- k7: w_out = [h_out[src], h_out[dst], w_bn, ow] @ W_aggre ----------------
__global__ __launch_bounds__(TB) void k7_mfma(const float* __restrict__ hout,
                                              const unsigned short* __restrict__ owH,
                                              const unsigned short* __restrict__ owL,
                                              const float* __restrict__ gamma,
                                              const float* __restrict__ beta,
                                              const unsigned short* __restrict__ wtH,
                                              const unsigned short* __restrict__ wtL,
                                              const int* __restrict__ src,
                                              const int* __restrict__ dst,
                                              float* __restrict__ w2out){
    __shared__ __align__(16) unsigned short Ah[4096], Al[4096], Bh[4096], Bl[4096];
    __shared__ float sGam[128], sBet[128];
    __shared__ int sSrc[128], sDst[128];
    const int tid = threadIdx.x;
    const long long rbase = (long long)blockIdx.x * 128;
    const int lane = tid & 63, w = tid >> 6;
    const int ls = lane & 15, lg = lane >> 4;
    const float ISR = 0.9999950000374997f;  // 1/sqrt(1+1e-5)
    if (tid < 128){
        sGam[tid] = gamma[tid] * ISR; sBet[tid] = beta[tid];
        sSrc[tid] = src[rbase + tid]; sDst[tid] = dst[rbase + tid];
    }
    f32x4 acc[2][8] = {};
    for (int kc = 0; kc < 512; kc += 32){
        __syncthreads();
#pragma unroll
        for (int u = 0; u < 2; ++u){
            int id = tid + u*256;
            int row = id >> 2, g = id & 3;
            int kk = kc + g*8;
            long long e = rbase + row;
            if (kk < 384){
                float4 v0, v1;
                if (kk < 128){
                    const float* p = &hout[(size_t)sSrc[row]*128 + kk];
                    v0 = *(const float4*)p; v1 = *(const float4*)(p+4);
                } else if (kk < 256){
                    const float* p = &hout[(size_t)sDst[row]*128 + (kk-128)];
                    v0 = *(const float4*)p; v1 = *(const float4*)(p+4);
                } else {
                    int cb = kk - 256;
                    const float* p = &w2out[e*128 + cb];
                    v0 = *(const float4*)p; v1 = *(const float4*)(p+4);
                    v0.x = fmaf(v0.x, sGam[cb+0], sBet[cb+0]);
                    v0.y = fmaf(v0.y, sGam[cb+1], sBet[cb+1]);
                    v0.z = fmaf(v0.z, sGam[cb+2], sBet[cb+2]);
                    v0.w = fmaf(v0.w, sGam[cb+3], sBet[cb+3]);
                    v1.x = fmaf(v1.x, sGam[cb+4], sBet[cb+4]);
                    v1.y = fmaf(v1.y, sGam[cb+5], sBet[cb+5]);
                    v1.z = fmaf(v1.z, sGam[cb+6], sBet[cb+6]);
                    v1.w = fmaf(v1.w, sGam[cb+7], sBet[cb+7]);
                }
                s8v hi, lo; split8(v0, v1, hi, lo);
                *(s8v*)&Ah[lds_a(row,g)] = hi; *(s8v*)&Al[lds_a(row,g)] = lo;
            } else {
                // ow quarter: pre-split bf16, direct LDS copy (no split VALU)
                *(s8v*)&Ah[lds_a(row,g)] = *(const s8v*)&owH[e*128 + (kk-384)];
                *(s8v*)&Al[lds_a(row,g)] = *(const s8v*)&owL[e*128 + (kk-384)];
            }
            int col = row;
            *(s8v*)&Bh[lds_a(col,g)] = *(const s8v*)&wtH[col*512 + kk];
            *(s8v*)&Bl[lds_a(col,g)] = *(const s8v*)&wtL[col*512 + kk];
        }
        __syncthreads();
        s8v ah[2], al[2];
#pragma unroll
        for (int rt = 0; rt < 2; ++rt){
            int r = w*32 + rt*16 + ls;
            ah[rt] = *(const s8v*)&Ah[lds_a(r,lg)];
            al[rt] = *(const s8v*)&Al[lds_a(r,lg)];
        }
#pragma unroll
        for (int ct = 0; ct < 8; ++ct){
            int c = ct*16 + ls;
            s8v bh = *(const s8v*)&Bh[lds_a(c,lg)];
            s8v bl = *(const s8v*)&Bl[lds_a(c,lg)];
#pragma unroll
            for (int rt = 0; rt < 2; ++rt){
                acc[rt][ct] = MFMA16(ah[rt], bh, acc[rt][ct]);
                acc[rt][ct] = MFMA16(ah[rt], bl, acc[rt][ct]);
                acc[rt][ct] = MFMA16(al[rt], bh, acc[rt][ct]);
            }
        }
    }
#pragma unroll
    for (int rt = 0; rt < 2; ++rt){
#pragma unroll
        for (int reg = 0; reg < 4; ++reg){
            long long orow = rbase + w*32 + rt*16 + lg*4 + reg;
#pragma unroll
            for (int ct = 0; ct < 8; ++ct)
                w2out[orow*128 + ct*16 + ls] = acc[rt][ct][reg];
        }
    }
}

extern "C" void kernel_launch(void* const* d_in, const int* in_sizes, int n_in,
                              void* d_out, int out_size, void* d_ws, size_t ws_size,
                              hipStream_t stream){
    (void)in_sizes; (void)n_in; (void)out_size;
    const float* h       = (const float*)d_in[0];
    const float* edge_w  = (const float*)d_in[1];
    const float* W_node  = (const float*)d_in[2];
    const float* W_eedge = (const float*)d_in[3];
    const float* W_esf   = (const float*)d_in[4];
    const float* W_fuse  = (const float*)d_in[5];
    const float* b_fuse  = (const float*)d_in[6];
    const float* W_attn  = (const float*)d_in[7];
    const float* W_conc  = (const float*)d_in[8];
    const float* b_conc  = (const float*)d_in[9];
    const float* gamma   = (const float*)d_in[10];
    const float* beta    = (const float*)d_in[11];
    const float* W_aggre = (const float*)d_in[12];
    const int*   src     = (const int*)d_in[13];
    const int*   dst     = (const int*)d_in[14];

    float* out    = (float*)d_out;
    float* o_hout = out + OUT_HOUT;
    float* o_wout = out + OUT_WOUT;
    float* o_sat  = out + OUT_SAT;

    if (ws_size < (size_t)WS_FLOATS * 4) return;
    float* ws     = (float*)d_ws;
    float* w_hn   = ws + OFF_HN;
    unsigned short* w_owH = (unsigned short*)(ws + OFF_OW);
    unsigned short* w_owL = w_owH + (size_t)NE*128;
    float* w_s    = ws + OFF_S;
    float* w_den  = ws + OFF_DEN;
    int*   w_cur  = (int*)(ws + OFF_CUR);
    float* w_hagg = ws + OFF_HAGG;
    unsigned short* w_wt = (unsigned short*)(ws + OFF_WT);

    int* w_eidx = (int*)o_hout;          // E ints (pre-k6 scratch)
    int* w_offs = w_eidx + NE;           // N ints

    hipLaunchKernelGGL(k_prep,    dim3(131072/TB), dim3(TB), 0, stream,
                       W_eedge, W_fuse, W_aggre, w_wt, w_cur);
    hipLaunchKernelGGL(kB_count,  dim3(NE/TB), dim3(TB), 0, stream, dst, w_cur);
    hipLaunchKernelGGL(kC_scan,   dim3(1), dim3(TB), 0, stream, w_cur, w_offs);
    hipLaunchKernelGGL(kD_scatter,dim3(NE/TB), dim3(TB), 0, stream, dst, w_cur, w_eidx);
    hipLaunchKernelGGL(k1_hn,     dim3((NN+BM-1)/BM), dim3(TB), 0, stream, h, W_node, w_hn);
    hipLaunchKernelGGL(k23_fuse,  dim3(NE/128), dim3(TB), 0, stream, edge_w,
                       w_wt + U_E, w_wt + U_E + 128*128, W_esf,
                       w_wt + U_F, w_wt + U_F + 128*384, b_fuse, W_attn,
                       src, dst, w_hn, w_owH, w_owL, o_sat, o_wout, w_s);
    hipLaunchKernelGGL(k5_agg,    dim3(NN), dim3(TB), 0, stream, w_s, w_hn, o_wout,
                       src, w_eidx, w_offs, w_cur, w_hagg, w_den);
    hipLaunchKernelGGL(k6_conc,   dim3((NN+BM-1)/BM), dim3(TB), 0, stream, w_hagg, w_hn,
                       W_conc, b_conc, w_den, o_hout);
    hipLaunchKernelGGL(k7_mfma,   dim3(NE/128), dim3(TB), 0, stream, o_hout,
                       w_owH, w_owL, gamma, beta,
                       w_wt + U_A, w_wt + U_A + 128*512,
                       src, dst, o_wout);
}

// Round 5
// 829.870 us; speedup vs baseline: 1.0967x; 1.0967x over previous
//
#include <hip/hip_runtime.h>
#include <hip/hip_bf16.h>

#define TB 256
#define TBM 512   // MFMA kernels: 8 waves/block
#define BM 64
#define BK 32
#define BN 128
#define ASTR 68   // BM + 4 (fp32 path, k1/k6)
#define MAXD 160  // per-node edge cache for k5

static constexpr int NN = 20000;
static constexpr int NE = 320000;

// workspace layout (floats)
static constexpr long long OFF_HN   = 0;          // N*128 fp32
static constexpr long long OFF_OW   = 2560000;    // owH/owL bf16: E*128 ushort each
static constexpr long long OFF_S    = 43520000;   // E  (raw attention scalar s)
static constexpr long long OFF_DEN  = 43840000;   // N
static constexpr long long OFF_CUR  = 43860000;   // N ints
static constexpr long long OFF_HAGG = 43880000;   // N*256  (ends 49,000,000)
static constexpr long long OFF_WT   = 49000000;   // split-bf16 transposed weights (ushort)
static constexpr long long WS_FLOATS = 49140000;  // ~196.6 MB (proven budget)

// Wt sub-offsets in ushort units from OFF_WT base
static constexpr int U_E = 0;        // W_eedge^T hi [128][128]; lo at +16384
static constexpr int U_F = 32768;    // W_fuse^T  hi [128][384]; lo at +49152
static constexpr int U_A = 131072;   // W_aggre^T hi [128][512]; lo at +65536

// d_out layout (floats): h_out, w_out, sat
static constexpr long long OUT_HOUT = 0;
static constexpr long long OUT_WOUT = 2560000;    // holds w2 until k7 overwrites with w_out
static constexpr long long OUT_SAT  = 43520000;

typedef __attribute__((ext_vector_type(8))) short s8v;      // 8 bf16 (4 VGPR)
typedef __attribute__((ext_vector_type(4))) float f32x4;

#define MFMA16(a,b,c) __builtin_amdgcn_mfma_f32_16x16x32_bf16(a,b,c,0,0,0)

__device__ __forceinline__ float lrelu(float x){ return x >= 0.f ? x : 0.1f*x; }

// ---- split fp32 -> (hi,lo) bf16, RNE both; hi+lo carries ~17 mantissa bits ----
__device__ __forceinline__ void split1(float f, unsigned short& hi, unsigned short& lo){
    __hip_bfloat16 h = __float2bfloat16(f);
    float hf = __bfloat162float(h);
    __hip_bfloat16 l = __float2bfloat16(f - hf);
    hi = __builtin_bit_cast(unsigned short, h);
    lo = __builtin_bit_cast(unsigned short, l);
}
__device__ __forceinline__ void split8(float4 a, float4 b, s8v& hi, s8v& lo){
    float v[8] = {a.x,a.y,a.z,a.w,b.x,b.y,b.z,b.w};
#pragma unroll
    for (int j = 0; j < 8; ++j){
        unsigned short hs, ls;
        split1(v[j], hs, ls);
        hi[j] = (short)hs; lo[j] = (short)ls;
    }
}

// LDS tile addressing: [128 rows][32 k] bf16, 16B-slot XOR swizzle (T2 family)
__device__ __forceinline__ int lds_a(int row, int g){
    return row*32 + ((g ^ (row & 3)) << 3);   // ushort index, 16B aligned
}

// ================= fp32 helpers for k1/k6 =================
__device__ __forceinline__ void store_At(float (*Ast)[ASTR], int k4, int r, float4 v){
    Ast[k4+0][r] = v.x; Ast[k4+1][r] = v.y; Ast[k4+2][r] = v.z; Ast[k4+3][r] = v.w;
}
__device__ __forceinline__ void mm_chunk(const float (*Ast)[ASTR], const float (*Bs)[BN],
                                         int r0, int c0, float acc[4][8]){
#pragma unroll 4
    for (int k = 0; k < BK; ++k){
        const float4 av = *(const float4*)&Ast[k][r0];
        const float4 b0 = *(const float4*)&Bs[k][c0];
        const float4 b1 = *(const float4*)&Bs[k][64 + c0];
        const float a0=av.x, a1=av.y, a2=av.z, a3=av.w;
        const float b[8] = {b0.x,b0.y,b0.z,b0.w,b1.x,b1.y,b1.z,b1.w};
#pragma unroll
        for (int j = 0; j < 8; ++j){
            acc[0][j] = fmaf(a0, b[j], acc[0][j]);
            acc[1][j] = fmaf(a1, b[j], acc[1][j]);
            acc[2][j] = fmaf(a2, b[j], acc[2][j]);
            acc[3][j] = fmaf(a3, b[j], acc[3][j]);
        }
    }
}
__device__ __forceinline__ void load_B(const float* __restrict__ W, int kc,
                                       float (*Bs)[BN], int tid){
#pragma unroll
    for (int p = 0; p < 4; ++p){
        int idx = p*TB + tid;
        int row = idx >> 5;
        int c4  = (idx & 31) << 2;
        *(float4*)&Bs[row][c4] = *(const float4*)&W[(size_t)(kc+row)*BN + c4];
    }
}

// block-wide reductions (k5)
__device__ __forceinline__ float blockMax(float v, float* sh4){
#pragma unroll
    for (int m = 32; m; m >>= 1) v = fmaxf(v, __shfl_xor(v, m));
    if ((threadIdx.x & 63) == 0) sh4[threadIdx.x >> 6] = v;
    __syncthreads();
    float r = fmaxf(fmaxf(sh4[0], sh4[1]), fmaxf(sh4[2], sh4[3]));
    __syncthreads();
    return r;
}
__device__ __forceinline__ float blockSum(float v, float* sh4){
#pragma unroll
    for (int m = 32; m; m >>= 1) v += __shfl_xor(v, m);
    if ((threadIdx.x & 63) == 0) sh4[threadIdx.x >> 6] = v;
    __syncthreads();
    float r = sh4[0] + sh4[1] + sh4[2] + sh4[3];
    __syncthreads();
    return r;
}

// ---------------- k_prep: cur init + all three weight transpose/splits ----------------
__global__ __launch_bounds__(TB) void k_prep(const float* __restrict__ We,
                                             const float* __restrict__ Wf,
                                             const float* __restrict__ Wa,
                                             unsigned short* __restrict__ wt,
                                             int* __restrict__ cur){
    int id = blockIdx.x*TB + threadIdx.x;   // grid covers 131072
    if (id < NN) cur[id] = 0;
    unsigned short hs, ls;
    if (id < 16384){                       // W_eedge: K=128
        int n = id >> 7, k = id & 127;
        split1(We[(size_t)k*128 + n], hs, ls);
        wt[U_E + id] = hs; wt[U_E + 16384 + id] = ls;
    } else if (id < 65536){                // W_fuse: K=384
        int local = id - 16384;
        int n = local / 384, k = local - n*384;
        split1(Wf[(size_t)k*128 + n], hs, ls);
        wt[U_F + local] = hs; wt[U_F + 49152 + local] = ls;
    } else if (id < 131072){               // W_aggre: K=512
        int local = id - 65536;
        int n = local >> 9, k = local & 511;
        split1(Wa[(size_t)k*128 + n], hs, ls);
        wt[U_A + local] = hs; wt[U_A + 65536 + local] = ls;
    }
}

// ---------------- sort pipeline ----------------
__global__ __launch_bounds__(TB) void kB_count(const int* __restrict__ dst,
                                               int* __restrict__ cur){
    int e = blockIdx.x*TB + threadIdx.x;
    atomicAdd(&cur[dst[e]], 1);
}
__global__ __launch_bounds__(TB) void kC_scan(int* __restrict__ cur,
                                              int* __restrict__ offs){
    __shared__ int part[TB];
    __shared__ int spre[TB];
    const int tid = threadIdx.x;
    const int CH = (NN + TB - 1) / TB;
    const int base = tid * CH;
    int sum = 0;
    for (int i = 0; i < CH; ++i){ int idx = base + i; if (idx < NN) sum += cur[idx]; }
    part[tid] = sum;
    __syncthreads();
    if (tid == 0){ int r = 0; for (int i = 0; i < TB; ++i){ spre[i] = r; r += part[i]; } }
    __syncthreads();
    int run = spre[tid];
    for (int i = 0; i < CH; ++i){
        int idx = base + i;
        if (idx < NN){ int c = cur[idx]; offs[idx] = run; cur[idx] = run; run += c; }
    }
}
__global__ __launch_bounds__(TB) void kD_scatter(const int* __restrict__ dst,
                                                 int* __restrict__ cur,
                                                 int* __restrict__ eidx){
    int e = blockIdx.x*TB + threadIdx.x;
    int p = atomicAdd(&cur[dst[e]], 1);
    eidx[p] = e;
}

// ---------------- k1: hn = h @ W_node (fp32 path) ----------------
__global__ __launch_bounds__(TB) void k1_hn(const float* __restrict__ h,
                                            const float* __restrict__ Wn,
                                            float* __restrict__ hn){
    __shared__ float Ast[BK][ASTR];
    __shared__ float Bs[BK][BN];
    const int tid = threadIdx.x;
    const int rbase = blockIdx.x * BM;
    const int tc = tid & 15, tr = tid >> 4;
    const int r0 = tr*4, c0 = tc*4;
    float acc[4][8] = {};
    for (int kc = 0; kc < 128; kc += BK){
        __syncthreads();
        {
            int lr = tid >> 3, k4 = (tid & 7) << 2;
#pragma unroll
            for (int p = 0; p < 2; ++p){
                int r = p*32 + lr;
                int rr = rbase + r; if (rr >= NN) rr = NN-1;
                float4 v = *(const float4*)&h[(size_t)rr*128 + kc + k4];
                store_At(Ast, k4, r, v);
            }
        }
        load_B(Wn, kc, Bs, tid);
        __syncthreads();
        mm_chunk(Ast, Bs, r0, c0, acc);
    }
#pragma unroll
    for (int i = 0; i < 4; ++i){
        int rr = rbase + r0 + i;
        if (rr < NN){
            float4 o0 = {acc[i][0],acc[i][1],acc[i][2],acc[i][3]};
            float4 o1 = {acc[i][4],acc[i][5],acc[i][6],acc[i][7]};
            *(float4*)&hn[(size_t)rr*128 + c0] = o0;
            *(float4*)&hn[(size_t)rr*128 + 64 + c0] = o1;
        }
    }
}

// ================== MFMA split-bf16 edge GEMMs: 512 thr, 8 waves, 128x128 tile ==================
// wave w owns rows w*16..w*16+15; acc f32x4[8] (one 16-row strip x 8 col-tiles)

// ---------------- k2: ow = edge_w @ W_eedge ; w1 = (lrelu(ow)@W_esf)*ow ----------------
__global__ __launch_bounds__(TBM) void k2_mfma(const float* __restrict__ ew,
                                               const unsigned short* __restrict__ wtH,
                                               const unsigned short* __restrict__ wtL,
                                               const float* __restrict__ Wesf,
                                               unsigned short* __restrict__ owH,
                                               unsigned short* __restrict__ owL,
                                               float* __restrict__ sat){
    __shared__ __align__(16) unsigned short Ah[4096], Al[4096], Bh[4096], Bl[4096];
    __shared__ float sEsf[128];
    const int tid = threadIdx.x;
    const long long rbase = (long long)blockIdx.x * 128;
    const int lane = tid & 63, w = tid >> 6;
    const int ls = lane & 15, lg = lane >> 4;
    const int srow = tid >> 2, sg = tid & 3;
    if (tid < 128) sEsf[tid] = Wesf[tid];
    f32x4 acc[8] = {};
    for (int kc = 0; kc < 128; kc += 32){
        __syncthreads();
        {
            int kk = kc + sg*8;
            const float* p = &ew[(rbase + srow)*128 + kk];
            float4 v0 = *(const float4*)p, v1 = *(const float4*)(p+4);
            s8v hi, lo; split8(v0, v1, hi, lo);
            *(s8v*)&Ah[lds_a(srow,sg)] = hi; *(s8v*)&Al[lds_a(srow,sg)] = lo;
            *(s8v*)&Bh[lds_a(srow,sg)] = *(const s8v*)&wtH[srow*128 + kk];
            *(s8v*)&Bl[lds_a(srow,sg)] = *(const s8v*)&wtL[srow*128 + kk];
        }
        __syncthreads();
        s8v ah = *(const s8v*)&Ah[lds_a(w*16 + ls, lg)];
        s8v al = *(const s8v*)&Al[lds_a(w*16 + ls, lg)];
#pragma unroll
        for (int ct = 0; ct < 8; ++ct){
            int c = ct*16 + ls;
            s8v bh = *(const s8v*)&Bh[lds_a(c,lg)];
            s8v bl = *(const s8v*)&Bl[lds_a(c,lg)];
            acc[ct] = MFMA16(ah, bh, acc[ct]);
            acc[ct] = MFMA16(ah, bl, acc[ct]);
            acc[ct] = MFMA16(al, bh, acc[ct]);
        }
    }
#pragma unroll
    for (int reg = 0; reg < 4; ++reg){
        float p = 0.f;
#pragma unroll
        for (int ct = 0; ct < 8; ++ct)
            p += lrelu(acc[ct][reg]) * sEsf[ct*16 + ls];
#pragma unroll
        for (int m = 1; m < 16; m <<= 1) p += __shfl_xor(p, m);
        long long orow = rbase + w*16 + lg*4 + reg;
#pragma unroll
        for (int ct = 0; ct < 8; ++ct){
            float o = acc[ct][reg];
            int col = ct*16 + ls;
            sat[orow*384 + 256 + col] = p * o;
            unsigned short hs_, ls_; split1(o, hs_, ls_);
            owH[orow*128 + col] = hs_;
            owL[orow*128 + col] = ls_;
        }
    }
}

// ---------------- k3: sat build + inw GEMM + attn dot + w2 + s ----------------
__global__ __launch_bounds__(TBM) void k3_mfma(const float* __restrict__ hn,
                                               const unsigned short* __restrict__ wtH,
                                               const unsigned short* __restrict__ wtL,
                                               const float* __restrict__ bf,
                                               const float* __restrict__ Wattn,
                                               const int* __restrict__ src,
                                               const int* __restrict__ dst,
                                               float* __restrict__ sat,
                                               float* __restrict__ w2,
                                               float* __restrict__ s_ws){
    __shared__ __align__(16) unsigned short Ah[4096], Al[4096], Bh[4096], Bl[4096];
    __shared__ float sBf[128], sAtt[128];
    __shared__ int sSrc[128], sDst[128];
    const int tid = threadIdx.x;
    const long long rbase = (long long)blockIdx.x * 128;
    const int lane = tid & 63, w = tid >> 6;
    const int ls = lane & 15, lg = lane >> 4;
    const int srow = tid >> 2, sg = tid & 3;
    if (tid < 128){
        sBf[tid] = bf[tid]; sAtt[tid] = Wattn[tid];
        sSrc[tid] = src[rbase + tid]; sDst[tid] = dst[rbase + tid];
    }
    f32x4 acc[8] = {};
    for (int kc = 0; kc < 384; kc += 32){
        __syncthreads();
        {
            int kk = kc + sg*8;
            long long e = rbase + srow;
            float4 v0, v1;
            if (kk < 128){
                const float* p = &hn[(size_t)sSrc[srow]*128 + kk];
                v0 = *(const float4*)p; v1 = *(const float4*)(p+4);
                *(float4*)&sat[e*384 + kk] = v0; *(float4*)&sat[e*384 + kk + 4] = v1;
            } else if (kk < 256){
                const float* p = &hn[(size_t)sDst[srow]*128 + (kk-128)];
                v0 = *(const float4*)p; v1 = *(const float4*)(p+4);
                *(float4*)&sat[e*384 + kk] = v0; *(float4*)&sat[e*384 + kk + 4] = v1;
            } else {
                const float* p = &sat[e*384 + kk];   // w1 (from k2)
                v0 = *(const float4*)p; v1 = *(const float4*)(p+4);
            }
            s8v hi, lo; split8(v0, v1, hi, lo);
            *(s8v*)&Ah[lds_a(srow,sg)] = hi; *(s8v*)&Al[lds_a(srow,sg)] = lo;
            *(s8v*)&Bh[lds_a(srow,sg)] = *(const s8v*)&wtH[srow*384 + kk];
            *(s8v*)&Bl[lds_a(srow,sg)] = *(const s8v*)&wtL[srow*384 + kk];
        }
        __syncthreads();
        s8v ah = *(const s8v*)&Ah[lds_a(w*16 + ls, lg)];
        s8v al = *(const s8v*)&Al[lds_a(w*16 + ls, lg)];
#pragma unroll
        for (int ct = 0; ct < 8; ++ct){
            int c = ct*16 + ls;
            s8v bh = *(const s8v*)&Bh[lds_a(c,lg)];
            s8v bl = *(const s8v*)&Bl[lds_a(c,lg)];
            acc[ct] = MFMA16(ah, bh, acc[ct]);
            acc[ct] = MFMA16(ah, bl, acc[ct]);
            acc[ct] = MFMA16(al, bh, acc[ct]);
        }
    }
    // epilogue: attn dot -> s; w2 = a * w1
#pragma unroll
    for (int reg = 0; reg < 4; ++reg){
        float p = 0.f;
#pragma unroll
        for (int ct = 0; ct < 8; ++ct){
            int col = ct*16 + ls;
            p += lrelu(acc[ct][reg] + sBf[col]) * sAtt[col];
        }
#pragma unroll
        for (int m = 1; m < 16; m <<= 1) p += __shfl_xor(p, m);
        long long orow = rbase + w*16 + lg*4 + reg;
        if (ls == 0) s_ws[orow] = p;
#pragma unroll
        for (int ct = 0; ct < 8; ++ct){
            int col = ct*16 + ls;
            float w1v = sat[orow*384 + 256 + col];   // L1/L2-hot (staged 2 K-steps ago)
            w2[orow*128 + col] = p * w1v;
        }
    }
}

// ---------------- k5: per-node softmax + gather-aggregate ----------------
__global__ __launch_bounds__(TB) void k5_agg(const float* __restrict__ s,
                                             const float* __restrict__ hn,
                                             const float* __restrict__ w2,
                                             const int* __restrict__ src,
                                             const int* __restrict__ eidx,
                                             const int* __restrict__ offs,
                                             const int* __restrict__ cur,
                                             float* __restrict__ hagg,
                                             float* __restrict__ den){
    __shared__ int   sE[MAXD];
    __shared__ int   sSrc[MAXD];
    __shared__ float sA[MAXD];
    __shared__ float sh4[4];
    const int n = blockIdx.x, tid = threadIdx.x;
    const int start = offs[n];
    const int deg = cur[n] - start;
    for (int i = tid; i < deg && i < MAXD; i += TB) sE[i] = eidx[start+i];
    __syncthreads();
    if (tid == 0 && deg > 1){
        int dd = deg < MAXD ? deg : MAXD;
        for (int i = 1; i < dd; ++i){
            int key = sE[i], j = i-1;
            while (j >= 0 && sE[j] > key){ sE[j+1] = sE[j]; --j; }
            sE[j+1] = key;
        }
    }
    __syncthreads();
    float lm = -3.402823466e38f;
    for (int i = tid; i < deg; i += TB){
        int e = (i < MAXD) ? sE[i] : eidx[start+i];
        lm = fmaxf(lm, s[e]);
    }
    const float m = blockMax(lm, sh4);
    float lsum = 0.f;
    for (int i = tid; i < deg; i += TB){
        int e = (i < MAXD) ? sE[i] : eidx[start+i];
        lsum += expf(s[e] - m);
    }
    const float denom = blockSum(lsum, sh4);
    for (int i = tid; i < deg && i < MAXD; i += TB){
        int e = sE[i];
        sA[i] = expf(s[e] - m) / denom;
        sSrc[i] = src[e];
    }
    __syncthreads();
    float acc = 0.f;
    const bool lo = tid < 128;
    for (int i = 0; i < deg; ++i){
        int e, sI; float a;
        if (i < MAXD){ e = sE[i]; a = sA[i]; sI = sSrc[i]; }
        else { e = eidx[start+i]; a = expf(s[e]-m)/denom; sI = src[e]; }
        float v = lo ? hn[(size_t)sI*128 + tid] : w2[(size_t)e*128 + (tid-128)];
        acc = fmaf(a, v, acc);
    }
    hagg[(size_t)n*256 + tid] = acc;
    if (tid == 0) den[n] = (deg > 0) ? denom : 0.f;
}

// ---------------- k6: h_new = [h_agg, hn] @ W_conc + b_conc ; indeg select ----------------
__global__ __launch_bounds__(TB) void k6_conc(const float* __restrict__ hagg,
                                              const float* __restrict__ hn,
                                              const float* __restrict__ Wc,
                                              const float* __restrict__ bc,
                                              const float* __restrict__ den,
                                              float* __restrict__ hout){
    __shared__ float Ast[BK][ASTR];
    __shared__ float Bs[BK][BN];
    __shared__ float sBc[BN];
    const int tid = threadIdx.x;
    const int rbase = blockIdx.x * BM;
    const int tc = tid & 15, tr = tid >> 4;
    const int r0 = tr*4, c0 = tc*4;
    if (tid < BN) sBc[tid] = bc[tid];
    float acc[4][8] = {};
    for (int chunk = 0; chunk < 12; ++chunk){
        int kc = chunk * BK;
        __syncthreads();
        {
            int lr = tid >> 3, k4 = (tid & 7) << 2;
#pragma unroll
            for (int p = 0; p < 2; ++p){
                int r = p*32 + lr;
                int rr = rbase + r; if (rr >= NN) rr = NN-1;
                float4 v;
                if (chunk < 8) v = *(const float4*)&hagg[(size_t)rr*256 + kc + k4];
                else           v = *(const float4*)&hn[(size_t)rr*128 + (kc-256) + k4];
                store_At(Ast, k4, r, v);
            }
        }
        load_B(Wc, kc, Bs, tid);
        __syncthreads();
        mm_chunk(Ast, Bs, r0, c0, acc);
    }
#pragma unroll
    for (int i = 0; i < 4; ++i){
        int rr = rbase + r0 + i;
        if (rr >= NN) continue;
        bool keep = den[rr] > 0.f;
        float4 h0 = *(const float4*)&hn[(size_t)rr*128 + c0];
        float4 h1 = *(const float4*)&hn[(size_t)rr*128 + 64 + c0];
        float4 o0, o1;
        o0.x = keep ? acc[i][0] + sBc[c0+0] : h0.x;
        o0.y = keep ? acc[i][1] + sBc[c0+1] : h0.y;
        o0.z = keep ? acc[i][2] + sBc[c0+2] : h0.z;
        o0.w = keep ? acc[i][3] + sBc[c0+3] : h0.w;
        o1.x = keep ? acc[i][4] + sBc[64+c0+0] : h1.x;
        o1.y = keep ? acc[i][5] + sBc[64+c0+1] : h1.y;
        o1.z = keep ? acc[i][6] + sBc[64+c0+2] : h1.z;
        o1.w = keep ? acc[i][7] + sBc[64+c0+3] : h1.w;
        *(float4*)&hout[(size_t)rr*128 + c0] = o0;
        *(float4*)&hout[(size_t)rr*128 + 64 + c0] = o1;
    }
}

// ---------------- k7: w_out = [h_out[src], h_out[dst], w_bn, ow] @ W_aggre ----------------
__global__ __launch_bounds__(TBM) void k7_mfma(const float* __restrict__ hout,
                                               const unsigned short* __restrict__ owH,
                                               const unsigned short* __restrict__ owL,
                                               const float* __restrict__ gamma,
                                               const float* __restrict__ beta,
                                               const unsigned short* __restrict__ wtH,
                                               const unsigned short* __restrict__ wtL,
                                               const int* __restrict__ src,
                                               const int* __restrict__ dst,
                                               float* __restrict__ w2out){
    __shared__ __align__(16) unsigned short Ah[4096], Al[4096], Bh[4096], Bl[4096];
    __shared__ float sGam[128], sBet[128];
    __shared__ int sSrc[128], sDst[128];
    const int tid = threadIdx.x;
    const long long rbase = (long long)blockIdx.x * 128;
    const int lane = tid & 63, w = tid >> 6;
    const int ls = lane & 15, lg = lane >> 4;
    const int srow = tid >> 2, sg = tid & 3;
    const float ISR = 0.9999950000374997f;  // 1/sqrt(1+1e-5)
    if (tid < 128){
        sGam[tid] = gamma[tid] * ISR; sBet[tid] = beta[tid];
        sSrc[tid] = src[rbase + tid]; sDst[tid] = dst[rbase + tid];
    }
    f32x4 acc[8] = {};
    for (int kc = 0; kc < 512; kc += 32){
        __syncthreads();
        {
            int kk = kc + sg*8;
            long long e = rbase + srow;
            if (kk < 384){
                float4 v0, v1;
                if (kk < 128){
                    const float* p = &hout[(size_t)sSrc[srow]*128 + kk];
                    v0 = *(const float4*)p; v1 = *(const float4*)(p+4);
                } else if (kk < 256){
                    const float* p = &hout[(size_t)sDst[srow]*128 + (kk-128)];
                    v0 = *(const float4*)p; v1 = *(const float4*)(p+4);
                } else {
                    int cb = kk - 256;
                    const float* p = &w2out[e*128 + cb];
                    v0 = *(const float4*)p; v1 = *(const float4*)(p+4);
                    v0.x = fmaf(v0.x, sGam[cb+0], sBet[cb+0]);
                    v0.y = fmaf(v0.y, sGam[cb+1], sBet[cb+1]);
                    v0.z = fmaf(v0.z, sGam[cb+2], sBet[cb+2]);
                    v0.w = fmaf(v0.w, sGam[cb+3], sBet[cb+3]);
                    v1.x = fmaf(v1.x, sGam[cb+4], sBet[cb+4]);
                    v1.y = fmaf(v1.y, sGam[cb+5], sBet[cb+5]);
                    v1.z = fmaf(v1.z, sGam[cb+6], sBet[cb+6]);
                    v1.w = fmaf(v1.w, sGam[cb+7], sBet[cb+7]);
                }
                s8v hi, lo; split8(v0, v1, hi, lo);
                *(s8v*)&Ah[lds_a(srow,sg)] = hi; *(s8v*)&Al[lds_a(srow,sg)] = lo;
            } else {
                // ow quarter: pre-split bf16, direct LDS copy (no split VALU)
                *(s8v*)&Ah[lds_a(srow,sg)] = *(const s8v*)&owH[e*128 + (kk-384)];
                *(s8v*)&Al[lds_a(srow,sg)] = *(const s8v*)&owL[e*128 + (kk-384)];
            }
            *(s8v*)&Bh[lds_a(srow,sg)] = *(const s8v*)&wtH[srow*512 + kk];
            *(s8v*)&Bl[lds_a(srow,sg)] = *(const s8v*)&wtL[srow*512 + kk];
        }
        __syncthreads();
        s8v ah = *(const s8v*)&Ah[lds_a(w*16 + ls, lg)];
        s8v al = *(const s8v*)&Al[lds_a(w*16 + ls, lg)];
#pragma unroll
        for (int ct = 0; ct < 8; ++ct){
            int c = ct*16 + ls;
            s8v bh = *(const s8v*)&Bh[lds_a(c,lg)];
            s8v bl = *(const s8v*)&Bl[lds_a(c,lg)];
            acc[ct] = MFMA16(ah, bh, acc[ct]);
            acc[ct] = MFMA16(ah, bl, acc[ct]);
            acc[ct] = MFMA16(al, bh, acc[ct]);
        }
    }
#pragma unroll
    for (int reg = 0; reg < 4; ++reg){
        long long orow = rbase + w*16 + lg*4 + reg;
#pragma unroll
        for (int ct = 0; ct < 8; ++ct)
            w2out[orow*128 + ct*16 + ls] = acc[ct][reg];
    }
}

extern "C" void kernel_launch(void* const* d_in, const int* in_sizes, int n_in,
                              void* d_out, int out_size, void* d_ws, size_t ws_size,
                              hipStream_t stream){
    (void)in_sizes; (void)n_in; (void)out_size;
    const float* h       = (const float*)d_in[0];
    const float* edge_w  = (const float*)d_in[1];
    const float* W_node  = (const float*)d_in[2];
    const float* W_eedge = (const float*)d_in[3];
    const float* W_esf   = (const float*)d_in[4];
    const float* W_fuse  = (const float*)d_in[5];
    const float* b_fuse  = (const float*)d_in[6];
    const float* W_attn  = (const float*)d_in[7];
    const float* W_conc  = (const float*)d_in[8];
    const float* b_conc  = (const float*)d_in[9];
    const float* gamma   = (const float*)d_in[10];
    const float* beta    = (const float*)d_in[11];
    const float* W_aggre = (const float*)d_in[12];
    const int*   src     = (const int*)d_in[13];
    const int*   dst     = (const int*)d_in[14];

    float* out    = (float*)d_out;
    float* o_hout = out + OUT_HOUT;
    float* o_wout = out + OUT_WOUT;
    float* o_sat  = out + OUT_SAT;

    if (ws_size < (size_t)WS_FLOATS * 4) return;
    float* ws     = (float*)d_ws;
    float* w_hn   = ws + OFF_HN;
    unsigned short* w_owH = (unsigned short*)(ws + OFF_OW);
    unsigned short* w_owL = w_owH + (size_t)NE*128;
    float* w_s    = ws + OFF_S;
    float* w_den  = ws + OFF_DEN;
    int*   w_cur  = (int*)(ws + OFF_CUR);
    float* w_hagg = ws + OFF_HAGG;
    unsigned short* w_wt = (unsigned short*)(ws + OFF_WT);

    int* w_eidx = (int*)o_hout;          // E ints (pre-k6 scratch)
    int* w_offs = w_eidx + NE;           // N ints

    hipLaunchKernelGGL(k_prep,    dim3(131072/TB), dim3(TB), 0, stream,
                       W_eedge, W_fuse, W_aggre, w_wt, w_cur);
    hipLaunchKernelGGL(kB_count,  dim3(NE/TB), dim3(TB), 0, stream, dst, w_cur);
    hipLaunchKernelGGL(kC_scan,   dim3(1), dim3(TB), 0, stream, w_cur, w_offs);
    hipLaunchKernelGGL(kD_scatter,dim3(NE/TB), dim3(TB), 0, stream, dst, w_cur, w_eidx);
    hipLaunchKernelGGL(k1_hn,     dim3((NN+BM-1)/BM), dim3(TB), 0, stream, h, W_node, w_hn);
    hipLaunchKernelGGL(k2_mfma,   dim3(NE/128), dim3(TBM), 0, stream, edge_w,
                       w_wt + U_E, w_wt + U_E + 128*128, W_esf,
                       w_owH, w_owL, o_sat);
    hipLaunchKernelGGL(k3_mfma,   dim3(NE/128), dim3(TBM), 0, stream, w_hn,
                       w_wt + U_F, w_wt + U_F + 128*384, b_fuse, W_attn,
                       src, dst, o_sat, o_wout, w_s);
    hipLaunchKernelGGL(k5_agg,    dim3(NN), dim3(TB), 0, stream, w_s, w_hn, o_wout,
                       src, w_eidx, w_offs, w_cur, w_hagg, w_den);
    hipLaunchKernelGGL(k6_conc,   dim3((NN+BM-1)/BM), dim3(TB), 0, stream, w_hagg, w_hn,
                       W_conc, b_conc, w_den, o_hout);
    hipLaunchKernelGGL(k7_mfma,   dim3(NE/128), dim3(TBM), 0, stream, o_hout,
                       w_owH, w_owL, gamma, beta,
                       w_wt + U_A, w_wt + U_A + 128*512,
                       src, dst, o_wout);
}